// Round 5
// baseline (6264.823 us; speedup 1.0000x reference)
//
#include <hip/hip_runtime.h>
#include <cstdint>
#include <cstddef>

// =====================================================================
// RBM Gibbs sampling, bit-exact replication of JAX-on-CPU reference.
// ROUND 15 = ROUND 14 (lane=b restructure) + compile fix: PKFMA macro
// choked on braced initializers (comma splits macro args); replaced
// with inline pkfma()/mk2() helpers, identical codegen intent.
// R14 design: lane=b in BOTH GEMMs. R13 counters showed sample_h
// LDS-throughput+barrier bound (4 broadcast b128 per k feeding 8
// pk_fma; VALU 45%, occ 37%); gemm_v same disease (~400us).
// New mapping: wave = 64 b (lane=b) x 16 h(v). f[b][k] computed
// per-lane in registers (byte-compare / bit-extract from padded LDS
// rows, conflict-free, 1 ds_read_b32 per 4 k / per 32 h). W row slice
// [h0..h0+15] is wave-uniform -> 4 uniform global_load_dwordx4 per k
// (L2-resident Wt/W). NO LDS broadcast, NO barriers in main loop.
// Per k: ~3 VALU f + 4 VMEM + 8 pk_fma (ratio ~2.3 vs R13 ~4.5).
// Bit-exactness: identical k-ascending fma chains, f in {0,1} exact
// (+/-0 adds, acc never -0.0), same slab folds at k%320==0, same RNG
// indices/expressions. Only the lane<->data mapping changed.
// Semantics FROZEN (rounds 6-13 passed, absmax=0):
//  - threefry2x32 partitionable; fold-like split; seed(42)->(0,42).
//  - cephes-Horner exp, Pommier-Horner log (q1/q2 tail), no contract.
//  - sigmoid = 1/(1+exp(-x)) IEEE div; gumbel tiny-clamp; first-max
//    argmax; bernoulli u<p; v-GEMM K=256 single sequential chain.
//  - h-GEMM: Eigen gebp kc=320 slab fold, k ascending (c-major).
// ws layout unchanged; sums scratch in out_v region (167.77MB exact);
// sentinel reads back ws_size as absmax if short.
// =====================================================================

#define B_DIM 16384
#define C_DIM 5
#define H_DIM 256
#define V_DIM 512

struct TFOut { uint32_t a, b; };

typedef float f32x2 __attribute__((ext_vector_type(2)));

static __device__ inline f32x2 mk2(float x, float y) {
  f32x2 r; r.x = x; r.y = y; return r;
}

static __device__ inline f32x2 pkfma(f32x2 a, f32x2 b, f32x2 c) {
#if __has_builtin(__builtin_elementwise_fma)
  return __builtin_elementwise_fma(a, b, c);
#else
  f32x2 r; r.x = fmaf(a.x, b.x, c.x); r.y = fmaf(a.y, b.y, c.y); return r;
#endif
}

__host__ __device__ static inline TFOut tf2x32(uint32_t k0, uint32_t k1,
                                               uint32_t c0, uint32_t c1) {
  uint32_t ks2 = k0 ^ k1 ^ 0x1BD11BDAu;
  uint32_t x0 = c0 + k0, x1 = c1 + k1;
#define TF_R(r) { x0 += x1; x1 = (x1 << r) | (x1 >> (32 - r)); x1 ^= x0; }
  TF_R(13) TF_R(15) TF_R(26) TF_R(6)
  x0 += k1;  x1 += ks2 + 1u;
  TF_R(17) TF_R(29) TF_R(16) TF_R(24)
  x0 += ks2; x1 += k0 + 2u;
  TF_R(13) TF_R(15) TF_R(26) TF_R(6)
  x0 += k0;  x1 += k1 + 3u;
  TF_R(17) TF_R(29) TF_R(16) TF_R(24)
  x0 += k1;  x1 += ks2 + 4u;
  TF_R(13) TF_R(15) TF_R(26) TF_R(6)
  x0 += ks2; x1 += k0 + 5u;
#undef TF_R
  TFOut o; o.a = x0; o.b = x1; return o;
}

// partitionable random_bits, 32-bit width, element index i (< 2^32)
__device__ static inline uint32_t rng_bits(uint32_t k0, uint32_t k1, uint32_t i) {
  TFOut r = tf2x32(k0, k1, 0u, i);
  return r.a ^ r.b;
}

__device__ static inline float bits_to_unit_float(uint32_t bits) {
  return __uint_as_float((bits >> 9) | 0x3F800000u) - 1.0f;
}

// XLA GenerateVF32Exp replica (cephes Horner port), mul+add separate,
// NO contraction.
__device__ static float xla_exp(float x_in) {
#pragma clang fp contract(off)
  float x = fminf(x_in, 88.3762626647950f);
  x = fmaxf(x, -88.3762626647949f);
  float fx = floorf(x * 1.44269504088896341f + 0.5f);
  float tmp = fx * 0.693359375f;
  float z = fx * -2.12194440e-4f;
  x = x - tmp;
  x = x - z;
  z = x * x;
  float y = 1.9875691500e-4f;
  y = y * x + 1.3981999507e-3f;
  y = y * x + 8.3334519073e-3f;
  y = y * x + 4.1665795894e-2f;
  y = y * x + 1.6666665459e-1f;
  y = y * x + 5.0000001201e-1f;
  y = y * z + x;
  y = y + 1.0f;
  int n = (int)fx;
  y = y * __uint_as_float((uint32_t)(n + 127) << 23);
  return y;
}

// XLA GenerateVF32Log replica = Pommier/Eigen3.3 log_ps (Horner + tail:
// y+=e*q1; y-=0.5*z; x+=y; x+=e*q2). NO contraction.
__device__ static float xla_log(float x_in) {
#pragma clang fp contract(off)
  float xv = fmaxf(x_in, 1.17549435e-38f);      // min_norm_pos clamp
  uint32_t bits = __float_as_uint(xv);
  float e = (float)((int)(bits >> 23) - 126);
  float x = __uint_as_float((bits & 0x007FFFFFu) | 0x3F000000u);  // [0.5,1)
  bool m = (x < 0.707106781186547524f);
  float tmp = m ? x : 0.0f;
  x = x - 1.0f;
  e = e - (m ? 1.0f : 0.0f);
  x = x + tmp;
  float z = x * x;
  float y = 7.0376836292e-2f;
  y = y * x + -1.1514610310e-1f;
  y = y * x + 1.1676998740e-1f;
  y = y * x + -1.2420140846e-1f;
  y = y * x + 1.4249322787e-1f;
  y = y * x + -1.6668057665e-1f;
  y = y * x + 2.0000714765e-1f;
  y = y * x + -2.4999993993e-1f;
  y = y * x + 3.3333331174e-1f;
  y = y * x;
  y = y * z;
  float t1 = e * -2.12194440e-4f;
  y = y + t1;
  float t2 = z * 0.5f;
  y = y - t2;
  x = x + y;
  float t3 = e * 0.693359375f;
  x = x + t3;
  return x;
}

// ---------------- kernels ----------------

__global__ void k_sentinel(float* out, float d) {
  out[0] = d;
}

// v0 one-hot (B,C,V) -> idx (B,V) u8
__global__ __launch_bounds__(256) void k_idx(const float* __restrict__ v0,
                                             uint8_t* __restrict__ idx) {
  int t = blockIdx.x * 256 + threadIdx.x;          // b*V + v
  int b = t >> 9, v = t & 511;
  const float* p = v0 + (size_t)b * (C_DIM * V_DIM) + v;
  int cf = 0;
#pragma unroll
  for (int c = 0; c < C_DIM; ++c)
    if (p[c * V_DIM] > 0.5f) cf = c;
  idx[t] = (uint8_t)cf;
}

// W (c,h,v) -> Wt (c,v,h)
__global__ __launch_bounds__(256) void k_wt(const float* __restrict__ W,
                                            float* __restrict__ Wt) {
  int t = blockIdx.x * 256 + threadIdx.x;          // (c, v, h)
  int h = t & 255; int rest = t >> 8; int v = rest & 511; int c = rest >> 9;
  Wt[t] = W[((size_t)c * H_DIM + h) * V_DIM + v];
}

// =====================================================================
// k_sample_h (lane=b): total[b][h] = sum_{k asc} Wt[k][h]*f[b][k],
// f = (idx[b][k&511] == k>>9), slab folds at k%320==0.
// Block = 64 b x 64 h (4 waves x 16 h). Per lane: b = b0+lane, 16 h acc
// as 8 f32x2. idx rows staged once to padded LDS rows (stride 129 u32,
// conflict-free per-lane reads, 1 ds_read_b32 per 4 k).
// W slice wave-uniform: 4 x global_load_dwordx4 per k (L2-resident).
// =====================================================================
__global__ __launch_bounds__(256, 4) void k_sample_h(
    const float* __restrict__ Wt, const float* __restrict__ c1g,
    const uint8_t* __restrict__ idx,
    float* __restrict__ out_h, uint32_t* __restrict__ out_mask,
    uint32_t key0, uint32_t key1) {
  __shared__ uint32_t sidx[64 * 129];     // row b at b*129 (padded)
  __shared__ uint16_t hb16[64][4];
  int t = threadIdx.x;
  int bg = blockIdx.x >> 2, hq = blockIdx.x & 3;
  int b0 = bg * 64;
  int wv = t >> 6, lane = t & 63;
  int h0 = hq * 64 + wv * 16;

  // stage idx rows (64 b x 512 u8) into padded LDS rows, coalesced
  {
    const uint32_t* src = (const uint32_t*)(idx + (size_t)b0 * V_DIM);
    for (int i = t; i < 64 * 128; i += 256) {
      int b = i >> 7, w = i & 127;
      sidx[b * 129 + w] = src[i];
    }
  }
  __syncthreads();

  const uint32_t* myrow = &sidx[lane * 129];
  const float* wbase = Wt + h0;

  f32x2 ps[8], tt[8];
#pragma unroll
  for (int j = 0; j < 8; ++j) {
    ps[j] = mk2(0.f, 0.f);
    tt[j] = mk2(0.f, 0.f);
  }

#pragma unroll 2
  for (int g = 0; g < 640; ++g) {         // k = 4g..4g+3
    if ((g % 80) == 0) {                  // slab boundary k%320==0
#pragma unroll
      for (int j = 0; j < 8; ++j) {
        tt[j] += ps[j];
        ps[j] = mk2(0.f, 0.f);
      }
    }
    uint32_t q = myrow[g & 127];          // 4 idx bytes (v = 4(g&127)+u)
    uint32_t cc = (uint32_t)(g >> 7);     // c = k>>9
    const float* wk = wbase + (size_t)(4 * g) * H_DIM;
#pragma unroll
    for (int u = 0; u < 4; ++u) {
      float f = (((q >> (8 * u)) & 255u) == cc) ? 1.0f : 0.0f;
      f32x2 ff = mk2(f, f);
      const float4* wr = (const float4*)(wk + (size_t)u * H_DIM);
      float4 wA = wr[0], wB = wr[1], wC = wr[2], wD = wr[3];
      ps[0] = pkfma(mk2(wA.x, wA.y), ff, ps[0]);
      ps[1] = pkfma(mk2(wA.z, wA.w), ff, ps[1]);
      ps[2] = pkfma(mk2(wB.x, wB.y), ff, ps[2]);
      ps[3] = pkfma(mk2(wB.z, wB.w), ff, ps[3]);
      ps[4] = pkfma(mk2(wC.x, wC.y), ff, ps[4]);
      ps[5] = pkfma(mk2(wC.z, wC.w), ff, ps[5]);
      ps[6] = pkfma(mk2(wD.x, wD.y), ff, ps[6]);
      ps[7] = pkfma(mk2(wD.z, wD.w), ff, ps[7]);
    }
  }
#pragma unroll
  for (int j = 0; j < 8; ++j) tt[j] += ps[j];   // final slab fold

  // ---- epilogue: sigmoid + bernoulli + out_h + mask ----
  int b = b0 + lane;
  const float4* c1q = (const float4*)(c1g + h0);
  float4 c1a = c1q[0], c1b = c1q[1], c1c = c1q[2], c1d = c1q[3];
  float tot[16], c1v[16], oh[16];
#pragma unroll
  for (int j = 0; j < 8; ++j) { tot[2 * j] = tt[j].x; tot[2 * j + 1] = tt[j].y; }
  c1v[0] = c1a.x;  c1v[1] = c1a.y;  c1v[2] = c1a.z;  c1v[3] = c1a.w;
  c1v[4] = c1b.x;  c1v[5] = c1b.y;  c1v[6] = c1b.z;  c1v[7] = c1b.w;
  c1v[8] = c1c.x;  c1v[9] = c1c.y;  c1v[10] = c1c.z; c1v[11] = c1c.w;
  c1v[12] = c1d.x; c1v[13] = c1d.y; c1v[14] = c1d.z; c1v[15] = c1d.w;
  uint32_t m16 = 0;
#pragma unroll
  for (int j = 0; j < 16; ++j) {
    float total = tot[j] + c1v[j];
    float p = 1.0f / (1.0f + xla_exp(-total));   // IEEE div, logistic form
    float u = bits_to_unit_float(
        rng_bits(key0, key1, (uint32_t)(b * H_DIM + h0 + j)));
    bool hbit = (u < p);
    oh[j] = hbit ? 1.0f : 0.0f;
    m16 |= (hbit ? 1u : 0u) << j;
  }
  if (out_h) {
    float4* dst = (float4*)(out_h + (size_t)b * H_DIM + h0);
#pragma unroll
    for (int q2 = 0; q2 < 4; ++q2) {
      float4 o;
      o.x = oh[4 * q2]; o.y = oh[4 * q2 + 1];
      o.z = oh[4 * q2 + 2]; o.w = oh[4 * q2 + 3];
      dst[q2] = o;
    }
  }
  hb16[lane][wv] = (uint16_t)m16;
  __syncthreads();
  if (t < 128) {
    int bl = t >> 1, half = t & 1;
    uint32_t wlo = hb16[bl][half * 2];
    uint32_t whi = hb16[bl][half * 2 + 1];
    out_mask[(size_t)(b0 + bl) * 8 + hq * 2 + half] = wlo | (whi << 16);
  }
}

// =====================================================================
// k_gemm_v (lane=b): sums[c][b][v] = h-ascending dense fma chain.
// Block = 64 b x 64 v (4 waves x 16 v). Per lane: b = b0+lane, 16 v acc
// as 8 f32x2 per c. Mask words in padded LDS rows (stride 9, conflict-
// free, 1 ds_read_b32 per 32 h). W slice wave-uniform: 4 x dwordx4/h.
// Chain per (b,v) identical to R11-R13 (bit-exact).
// =====================================================================
__global__ __launch_bounds__(256, 4) void k_gemm_v(
    const float* __restrict__ W, const uint32_t* __restrict__ mask,
    float* __restrict__ sums) {
  __shared__ uint32_t smask[64 * 9];      // row b at b*9 (padded)
  int t = threadIdx.x;
  int bg = blockIdx.x >> 3, vq = blockIdx.x & 7;
  int b0 = bg * 64;
  int wv = t >> 6, lane = t & 63;
  int v0 = vq * 64 + wv * 16;

  for (int i = t; i < 512; i += 256) {    // 64 b x 8 words, coalesced
    int b = i >> 3, w = i & 7;
    smask[b * 9 + w] = mask[(size_t)b0 * 8 + i];
  }
  __syncthreads();

  const uint32_t* mrow = &smask[lane * 9];
  const float* wbase = W + v0;

  for (int c = 0; c < C_DIM; ++c) {
    f32x2 acc[8];
#pragma unroll
    for (int j = 0; j < 8; ++j) acc[j] = mk2(0.f, 0.f);
    for (int hc = 0; hc < 8; ++hc) {
      uint32_t word = mrow[hc];
      const float* wp = wbase + ((size_t)c * H_DIM + hc * 32) * V_DIM;
#pragma unroll
      for (int hb = 0; hb < 32; ++hb) {
        float f = (float)((word >> hb) & 1u);
        f32x2 ff = mk2(f, f);
        const float4* wr = (const float4*)(wp + (size_t)hb * V_DIM);
        float4 wA = wr[0], wB = wr[1], wC = wr[2], wD = wr[3];
        acc[0] = pkfma(mk2(wA.x, wA.y), ff, acc[0]);
        acc[1] = pkfma(mk2(wA.z, wA.w), ff, acc[1]);
        acc[2] = pkfma(mk2(wB.x, wB.y), ff, acc[2]);
        acc[3] = pkfma(mk2(wB.z, wB.w), ff, acc[3]);
        acc[4] = pkfma(mk2(wC.x, wC.y), ff, acc[4]);
        acc[5] = pkfma(mk2(wC.z, wC.w), ff, acc[5]);
        acc[6] = pkfma(mk2(wD.x, wD.y), ff, acc[6]);
        acc[7] = pkfma(mk2(wD.z, wD.w), ff, acc[7]);
      }
    }
    float* srow = sums + ((size_t)c * B_DIM + b0 + lane) * V_DIM + v0;
    float4 o0, o1, o2, o3;
    o0.x = acc[0].x; o0.y = acc[0].y; o0.z = acc[1].x; o0.w = acc[1].y;
    o1.x = acc[2].x; o1.y = acc[2].y; o1.z = acc[3].x; o1.w = acc[3].y;
    o2.x = acc[4].x; o2.y = acc[4].y; o2.z = acc[5].x; o2.w = acc[5].y;
    o3.x = acc[6].x; o3.y = acc[6].y; o3.z = acc[7].x; o3.w = acc[7].y;
    float4* sdst = (float4*)srow;
    sdst[0] = o0; sdst[1] = o1; sdst[2] = o2; sdst[3] = o3;
  }
}

// =====================================================================
// k_gumbel_v: v = categorical over c (gumbel + first-max argmax),
// reading the staged sums. Expressions/RNG identical to R11 epilogue.
// =====================================================================
__global__ __launch_bounds__(256, 4) void k_gumbel_v(
    const float* __restrict__ sums, const float* __restrict__ b2,
    uint8_t* __restrict__ idx_out, uint32_t key0, uint32_t key1) {
  int gidx = blockIdx.x * 256 + threadIdx.x;
  int b = gidx >> 7;
  int v0 = (gidx & 127) << 2;
  float best[4];
  uint32_t bc = 0;
#pragma unroll
  for (int c = 0; c < C_DIM; ++c) {
    float4 av = *(const float4*)&sums[((size_t)c * B_DIM + b) * V_DIM + v0];
    float4 bv = *(const float4*)&b2[c * V_DIM + v0];
    uint32_t ib = ((uint32_t)b * C_DIM + (uint32_t)c) * V_DIM + (uint32_t)v0;
    float avq[4] = {av.x, av.y, av.z, av.w};
    float bvq[4] = {bv.x, bv.y, bv.z, bv.w};
#pragma unroll
    for (int q = 0; q < 4; ++q) {
      float uf = bits_to_unit_float(rng_bits(key0, key1, ib + (uint32_t)q));
      if (uf == 0.0f) uf = 1.17549435e-38f;        // u + tiny semantics
      float gz = -xla_log(-xla_log(uf));
      float z = gz + (avq[q] + bvq[q]);
      if (c == 0 || z > best[q]) {
        best[q] = z;
        bc = (bc & ~(0xFFu << (8 * q))) | ((uint32_t)c << (8 * q));
      }
    }
  }
  *(uint32_t*)(idx_out + (size_t)b * V_DIM + v0) = bc;
}

// idx -> one-hot f32 (B,C,V)
__global__ __launch_bounds__(256) void k_onehot(const uint8_t* __restrict__ idx,
                                                float* __restrict__ out) {
  int t = blockIdx.x * 256 + threadIdx.x;     // b*C*V + c*V + v
  int v = t & 511; int rest = t >> 9; int c = rest % C_DIM; int b = rest / C_DIM;
  out[t] = (idx[(size_t)b * V_DIM + v] == c) ? 1.0f : 0.0f;
}

// ---------------- launch ----------------

extern "C" void kernel_launch(void* const* d_in, const int* in_sizes, int n_in,
                              void* d_out, int out_size, void* d_ws, size_t ws_size,
                              hipStream_t stream) {
  float* out = (float*)d_out;

  // ---- structural sentinels ----
  const size_t WS_NEED = 2621440ull      // Wt
                       + 2621440ull      // (reserved, layout kept)
                       + 8388608ull      // idx
                       + 524288ull;      // mask  = 14,155,776 B
  float D = 0.0f;
  if (n_in < 4)                       D = 910.0f + (float)n_in;
  else if (in_sizes[0] != 41943040)   D = 920.0f;
  else if (in_sizes[1] != 655360)     D = 921.0f;
  else if (in_sizes[2] != 2560)       D = 922.0f;
  else if (in_sizes[3] != 256)        D = 923.0f;
  else if (out_size != 50331648)      D = 930.0f + (float)out_size * 1e-6f;
  else if (ws_size < WS_NEED)         D = 100.0f + (float)(ws_size >> 20);
  if (D != 0.0f) {
    hipLaunchKernelGGL(k_sentinel, dim3(1), dim3(1), 0, stream, out, D);
    return;
  }

  const float* v0 = (const float*)d_in[0];
  const float* W  = (const float*)d_in[1];
  const float* b2 = (const float*)d_in[2];   // (C,V)
  const float* c1 = (const float*)d_in[3];   // (H)

  float* out_v  = out;                                         // B*C*V
  float* out_h  = out + (size_t)B_DIM * C_DIM * V_DIM;         // B*H (final h)
  float* out_h0 = out_h + (size_t)B_DIM * H_DIM;               // B*H (h|v0)

  char* ws = (char*)d_ws;
  float*    Wt   = (float*)(ws);                    // 2,621,440 B
  uint8_t*  idx  = (uint8_t*)(ws + 5242880);        // 8,388,608 B
  uint32_t* mask = (uint32_t*)(ws + 13631488);      //   524,288 B

  // sums scratch lives in the out_v region (167.77MB, exact fit);
  // k_onehot overwrites it as the final kernel.
  float* sums = out_v;

  // partitionable (fold-like) split of key(42) into 5 subkeys
  uint32_t keys[5][2];
  for (int i = 0; i < 5; ++i) {
    TFOut r = tf2x32(0u, 42u, 0u, (uint32_t)i);
    keys[i][0] = r.a; keys[i][1] = r.b;
  }

  hipLaunchKernelGGL(k_wt,  dim3(2560),  dim3(256), 0, stream, W, Wt);
  hipLaunchKernelGGL(k_idx, dim3(32768), dim3(256), 0, stream, v0, idx);

  // h0 = sample_h(keys[0], v0) -> h_given_v0 output + mask
  hipLaunchKernelGGL(k_sample_h, dim3(B_DIM / 64 * 4), dim3(256), 0, stream,
                     Wt, c1, idx, out_h0, mask, keys[0][0], keys[0][1]);
  // iter 0: v = sample_v(keys[1], h0); h1 = sample_h(keys[2], v)
  hipLaunchKernelGGL(k_gemm_v, dim3(B_DIM / 64 * 8), dim3(256), 0, stream,
                     W, mask, sums);
  hipLaunchKernelGGL(k_gumbel_v, dim3(B_DIM * 128 / 256), dim3(256), 0, stream,
                     sums, b2, idx, keys[1][0], keys[1][1]);
  hipLaunchKernelGGL(k_sample_h, dim3(B_DIM / 64 * 4), dim3(256), 0, stream,
                     Wt, c1, idx, (float*)nullptr, mask, keys[2][0], keys[2][1]);
  // iter 1: v = sample_v(keys[3], h1); h2 = sample_h(keys[4], v)
  hipLaunchKernelGGL(k_gemm_v, dim3(B_DIM / 64 * 8), dim3(256), 0, stream,
                     W, mask, sums);
  hipLaunchKernelGGL(k_gumbel_v, dim3(B_DIM * 128 / 256), dim3(256), 0, stream,
                     sums, b2, idx, keys[3][0], keys[3][1]);
  hipLaunchKernelGGL(k_sample_h, dim3(B_DIM / 64 * 4), dim3(256), 0, stream,
                     Wt, c1, idx, out_h, mask, keys[4][0], keys[4][1]);
  // final v one-hot output
  hipLaunchKernelGGL(k_onehot, dim3(163840), dim3(256), 0, stream, idx, out_v);
}

// Round 6
// 2032.830 us; speedup vs baseline: 3.0818x; 3.0818x over previous
//
#include <hip/hip_runtime.h>
#include <cstdint>
#include <cstddef>

// =====================================================================
// RBM Gibbs sampling, bit-exact replication of JAX-on-CPU reference.
// ROUND 16 (perf): assemble best-measured parts.
// - k_sample_h: REVERT to R11 sparse per-b kernel (measured ~300us;
//   ~80% of its L2-traffic floor). R13 dense (421us) was LDS-issue
//   bound; R15 lane=b (est ~1000us) was VMEM-latency bound (VALU 17%,
//   VGPR 40, wave-uniform loads with no MLP). Measured lesson: f in
//   LDS-broadcast, W in per-lane coalesced streams.
// - k_gemm_v: R13 structure (tbf[h][16] floats in LDS, per-lane
//   coalesced float2 W loads, 16 b as 8 pk pairs) + h-unroll 8 for
//   2x W-load MLP (R15's latency lesson applied where it helps).
// - k_gumbel_v / k_idx / k_wt / k_onehot unchanged (R13).
// Bit-exactness unchanged: gemm = h-ascending fma chain, f in {0,1}
// exact (+/-0 adds, acc never -0.0); sums f32 round-trip exact;
// gumbel expressions/RNG indices identical; sample_h = R11 verbatim.
// Semantics FROZEN (rounds 6-13,15 passed, absmax=0):
//  - threefry2x32 partitionable; fold-like split; seed(42)->(0,42).
//  - cephes-Horner exp, Pommier-Horner log (q1/q2 tail), no contract.
//  - sigmoid = 1/(1+exp(-x)) IEEE div; gumbel tiny-clamp; first-max
//    argmax; bernoulli u<p; v-GEMM K=256 single sequential chain.
//  - h-GEMM: Eigen gebp kc=320 slab fold, k ascending (c-major).
// ws layout unchanged; sums scratch in out_v region (167.77MB exact);
// sentinel reads back ws_size as absmax if short.
// =====================================================================

#define B_DIM 16384
#define C_DIM 5
#define H_DIM 256
#define V_DIM 512
#define KC    320   // Eigen MT gebp kc (Zen5 48KB L1d: min(435,320)=320)

struct TFOut { uint32_t a, b; };

typedef float f32x2 __attribute__((ext_vector_type(2)));
typedef float f32x4 __attribute__((ext_vector_type(4)));

static __device__ inline f32x2 mk2(float x, float y) {
  f32x2 r; r.x = x; r.y = y; return r;
}

static __device__ inline f32x2 pkfma(f32x2 a, f32x2 b, f32x2 c) {
#if __has_builtin(__builtin_elementwise_fma)
  return __builtin_elementwise_fma(a, b, c);
#else
  f32x2 r; r.x = fmaf(a.x, b.x, c.x); r.y = fmaf(a.y, b.y, c.y); return r;
#endif
}

__host__ __device__ static inline TFOut tf2x32(uint32_t k0, uint32_t k1,
                                               uint32_t c0, uint32_t c1) {
  uint32_t ks2 = k0 ^ k1 ^ 0x1BD11BDAu;
  uint32_t x0 = c0 + k0, x1 = c1 + k1;
#define TF_R(r) { x0 += x1; x1 = (x1 << r) | (x1 >> (32 - r)); x1 ^= x0; }
  TF_R(13) TF_R(15) TF_R(26) TF_R(6)
  x0 += k1;  x1 += ks2 + 1u;
  TF_R(17) TF_R(29) TF_R(16) TF_R(24)
  x0 += ks2; x1 += k0 + 2u;
  TF_R(13) TF_R(15) TF_R(26) TF_R(6)
  x0 += k0;  x1 += k1 + 3u;
  TF_R(17) TF_R(29) TF_R(16) TF_R(24)
  x0 += k1;  x1 += ks2 + 4u;
  TF_R(13) TF_R(15) TF_R(26) TF_R(6)
  x0 += ks2; x1 += k0 + 5u;
#undef TF_R
  TFOut o; o.a = x0; o.b = x1; return o;
}

// partitionable random_bits, 32-bit width, element index i (< 2^32)
__device__ static inline uint32_t rng_bits(uint32_t k0, uint32_t k1, uint32_t i) {
  TFOut r = tf2x32(k0, k1, 0u, i);
  return r.a ^ r.b;
}

__device__ static inline float bits_to_unit_float(uint32_t bits) {
  return __uint_as_float((bits >> 9) | 0x3F800000u) - 1.0f;
}

// XLA GenerateVF32Exp replica (cephes Horner port), mul+add separate,
// NO contraction.
__device__ static float xla_exp(float x_in) {
#pragma clang fp contract(off)
  float x = fminf(x_in, 88.3762626647950f);
  x = fmaxf(x, -88.3762626647949f);
  float fx = floorf(x * 1.44269504088896341f + 0.5f);
  float tmp = fx * 0.693359375f;
  float z = fx * -2.12194440e-4f;
  x = x - tmp;
  x = x - z;
  z = x * x;
  float y = 1.9875691500e-4f;
  y = y * x + 1.3981999507e-3f;
  y = y * x + 8.3334519073e-3f;
  y = y * x + 4.1665795894e-2f;
  y = y * x + 1.6666665459e-1f;
  y = y * x + 5.0000001201e-1f;
  y = y * z + x;
  y = y + 1.0f;
  int n = (int)fx;
  y = y * __uint_as_float((uint32_t)(n + 127) << 23);
  return y;
}

// XLA GenerateVF32Log replica = Pommier/Eigen3.3 log_ps (Horner + tail:
// y+=e*q1; y-=0.5*z; x+=y; x+=e*q2). NO contraction.
__device__ static float xla_log(float x_in) {
#pragma clang fp contract(off)
  float xv = fmaxf(x_in, 1.17549435e-38f);      // min_norm_pos clamp
  uint32_t bits = __float_as_uint(xv);
  float e = (float)((int)(bits >> 23) - 126);
  float x = __uint_as_float((bits & 0x007FFFFFu) | 0x3F000000u);  // [0.5,1)
  bool m = (x < 0.707106781186547524f);
  float tmp = m ? x : 0.0f;
  x = x - 1.0f;
  e = e - (m ? 1.0f : 0.0f);
  x = x + tmp;
  float z = x * x;
  float y = 7.0376836292e-2f;
  y = y * x + -1.1514610310e-1f;
  y = y * x + 1.1676998740e-1f;
  y = y * x + -1.2420140846e-1f;
  y = y * x + 1.4249322787e-1f;
  y = y * x + -1.6668057665e-1f;
  y = y * x + 2.0000714765e-1f;
  y = y * x + -2.4999993993e-1f;
  y = y * x + 3.3333331174e-1f;
  y = y * x;
  y = y * z;
  float t1 = e * -2.12194440e-4f;
  y = y + t1;
  float t2 = z * 0.5f;
  y = y - t2;
  x = x + y;
  float t3 = e * 0.693359375f;
  x = x + t3;
  return x;
}

// ---------------- kernels ----------------

__global__ void k_sentinel(float* out, float d) {
  out[0] = d;
}

// v0 one-hot (B,C,V) -> idx (B,V) u8
__global__ __launch_bounds__(256) void k_idx(const float* __restrict__ v0,
                                             uint8_t* __restrict__ idx) {
  int t = blockIdx.x * 256 + threadIdx.x;          // b*V + v
  int b = t >> 9, v = t & 511;
  const float* p = v0 + (size_t)b * (C_DIM * V_DIM) + v;
  int cf = 0;
#pragma unroll
  for (int c = 0; c < C_DIM; ++c)
    if (p[c * V_DIM] > 0.5f) cf = c;
  idx[t] = (uint8_t)cf;
}

// W (c,h,v) -> Wt (c,v,h)
__global__ __launch_bounds__(256) void k_wt(const float* __restrict__ W,
                                            float* __restrict__ Wt) {
  int t = blockIdx.x * 256 + threadIdx.x;          // (c, v, h)
  int h = t & 255; int rest = t >> 8; int v = rest & 511; int c = rest >> 9;
  Wt[t] = W[((size_t)c * H_DIM + h) * V_DIM + v];
}

// =====================================================================
// k_sample_h: R11 sparse per-b kernel (reverted, measured ~300us).
// h = bernoulli(sigmoid(kc-slab-folded k-ascending sum + c1)).
// In-LDS compaction: soff[512] = selected k offsets asc, jb[s] =
// kc-panel boundaries. Order bit-identical to rounds 6-11.
// =====================================================================
__global__ __launch_bounds__(256) void k_sample_h(
    const float* __restrict__ Wt, const float* __restrict__ c1,
    const uint8_t* __restrict__ idx,
    float* __restrict__ out_h, uint32_t* __restrict__ out_mask,
    uint32_t key0, uint32_t key1) {
  __shared__ uint8_t  sidx[V_DIM];
  __shared__ uint32_t soff[V_DIM];     // (c*512+v)*1024 byte offsets, k asc
  __shared__ uint16_t cnt[8][5];       // per 64-lane segment, per class
  __shared__ uint16_t base[8][5];      // global start position
  __shared__ uint16_t jb[10];          // panel boundaries in j-space
  int b = blockIdx.x;
  int t = threadIdx.x;
  if (t < 128)
    ((uint32_t*)sidx)[t] = ((const uint32_t*)(idx + (size_t)b * V_DIM))[t];
  __syncthreads();

  int lane = t & 63, wv = t >> 6;
  int v0 = t,       c0 = sidx[v0];
  int v1 = t + 256, c1i = sidx[v1];
  int rank0, rank1;
  {
    unsigned long long bal[5];
#pragma unroll
    for (int cc = 0; cc < 5; ++cc) bal[cc] = __ballot(c0 == cc);
    if (lane == 0) {
#pragma unroll
      for (int cc = 0; cc < 5; ++cc) cnt[wv][cc] = (uint16_t)__popcll(bal[cc]);
    }
    rank0 = (int)__popcll(bal[c0] & ((1ull << lane) - 1ull));
  }
  {
    unsigned long long bal[5];
#pragma unroll
    for (int cc = 0; cc < 5; ++cc) bal[cc] = __ballot(c1i == cc);
    if (lane == 0) {
#pragma unroll
      for (int cc = 0; cc < 5; ++cc) cnt[4 + wv][cc] = (uint16_t)__popcll(bal[cc]);
    }
    rank1 = (int)__popcll(bal[c1i] & ((1ull << lane) - 1ull));
  }
  __syncthreads();
  if (t == 0) {
    int pos = 0;
    for (int cc = 0; cc < 5; ++cc)
      for (int g = 0; g < 8; ++g) { base[g][cc] = (uint16_t)pos; pos += cnt[g][cc]; }
  }
  __syncthreads();
  soff[base[wv][c0] + rank0]       = (uint32_t)(c0 * V_DIM + v0) << 10;   // k*1024B
  soff[base[4 + wv][c1i] + rank1]  = (uint32_t)(c1i * V_DIM + v1) << 10;
  __syncthreads();
  if (t < 10) {
    uint32_t target = (uint32_t)(t * KC) << 10;
    int lo = 0, hi = V_DIM;
    while (lo < hi) { int mid = (lo + hi) >> 1;
      if (soff[mid] < target) lo = mid + 1; else hi = mid; }
    jb[t] = (uint16_t)lo;
  }
  __syncthreads();

  // main accumulation: h = t
  const char* Wh = (const char*)Wt + (size_t)t * 4;
  float total = 0.0f;
  for (int s = 0; s < 9; ++s) {
    int j = jb[s], jend = jb[s + 1];
    float psum = 0.0f;
    for (; j + 4 <= jend; j += 4) {
      float w0 = *(const float*)(Wh + soff[j]);
      float w1 = *(const float*)(Wh + soff[j + 1]);
      float w2 = *(const float*)(Wh + soff[j + 2]);
      float w3 = *(const float*)(Wh + soff[j + 3]);
      psum += w0; psum += w1; psum += w2; psum += w3;
    }
    for (; j < jend; ++j) psum += *(const float*)(Wh + soff[j]);
    total += psum;
  }

  float tt = total + c1[t];
  float p = 1.0f / (1.0f + xla_exp(-tt));   // IEEE div, logistic exp form

  uint32_t i = (uint32_t)(b * H_DIM + t);
  float u = bits_to_unit_float(rng_bits(key0, key1, i));
  bool hb = (u < p);
  if (out_h) out_h[(size_t)b * H_DIM + t] = hb ? 1.0f : 0.0f;

  unsigned long long m = __ballot(hb);
  if ((t & 63) == 0) {
    out_mask[(size_t)b * 8 + wv * 2 + 0] = (uint32_t)(m & 0xFFFFFFFFull);
    out_mask[(size_t)b * 8 + wv * 2 + 1] = (uint32_t)(m >> 32);
  }
}

// =====================================================================
// k_gemm_v: sums[c][b][v] = h-ascending dense fma chain (f in {0,1}).
// Block = 16 b x 512 v; thread = 16 b (8 pk pairs) x 2 v.  Per h:
// 1 float2 W load + 4 broadcast ds_read_b128 + 16 pk_fma. h-unroll 8
// keeps 8 W loads (2KB/wave) in flight. Chain identical to R11-R13.
// =====================================================================
static __device__ inline void gv_h(float2 w2, const float* tbf_row,
                                   f32x2* av0, f32x2* av1) {
  f32x2 ww0 = mk2(w2.x, w2.x);
  f32x2 ww1 = mk2(w2.y, w2.y);
  const f32x4* fp = (const f32x4*)tbf_row;
  f32x4 qA = fp[0], qB = fp[1], qC = fp[2], qD = fp[3];
  f32x2 f0 = __builtin_shufflevector(qA, qA, 0, 1);
  f32x2 f1 = __builtin_shufflevector(qA, qA, 2, 3);
  f32x2 f2 = __builtin_shufflevector(qB, qB, 0, 1);
  f32x2 f3 = __builtin_shufflevector(qB, qB, 2, 3);
  f32x2 f4 = __builtin_shufflevector(qC, qC, 0, 1);
  f32x2 f5 = __builtin_shufflevector(qC, qC, 2, 3);
  f32x2 f6 = __builtin_shufflevector(qD, qD, 0, 1);
  f32x2 f7 = __builtin_shufflevector(qD, qD, 2, 3);
  av0[0] = pkfma(ww0, f0, av0[0]); av1[0] = pkfma(ww1, f0, av1[0]);
  av0[1] = pkfma(ww0, f1, av0[1]); av1[1] = pkfma(ww1, f1, av1[1]);
  av0[2] = pkfma(ww0, f2, av0[2]); av1[2] = pkfma(ww1, f2, av1[2]);
  av0[3] = pkfma(ww0, f3, av0[3]); av1[3] = pkfma(ww1, f3, av1[3]);
  av0[4] = pkfma(ww0, f4, av0[4]); av1[4] = pkfma(ww1, f4, av1[4]);
  av0[5] = pkfma(ww0, f5, av0[5]); av1[5] = pkfma(ww1, f5, av1[5]);
  av0[6] = pkfma(ww0, f6, av0[6]); av1[6] = pkfma(ww1, f6, av1[6]);
  av0[7] = pkfma(ww0, f7, av0[7]); av1[7] = pkfma(ww1, f7, av1[7]);
}

__global__ __launch_bounds__(256, 4) void k_gemm_v(
    const float* __restrict__ W, const uint32_t* __restrict__ mask,
    float* __restrict__ sums) {
  __shared__ uint32_t smask[16][8];
  __shared__ __align__(16) float tbf[H_DIM][16];
  int t = threadIdx.x;
  int b0 = blockIdx.x * 16;
  if (t < 128) smask[t >> 3][t & 7] = mask[(size_t)b0 * 8 + t];
  __syncthreads();
  {
    int h = t;
    uint32_t w = (uint32_t)(h >> 5), s = (uint32_t)(h & 31), x = 0;
#pragma unroll
    for (int j = 0; j < 16; ++j)
      x |= ((smask[j][w] >> s) & 1u) << j;
#pragma unroll
    for (int i = 0; i < 16; ++i)
      tbf[h][i] = (float)((x >> i) & 1u);
  }
  __syncthreads();

  int wv = t >> 6, lane = t & 63;
  int v0 = wv * 128 + (lane << 1);

  for (int c = 0; c < C_DIM; ++c) {
    f32x2 av0[8], av1[8];
#pragma unroll
    for (int j = 0; j < 8; ++j) {
      av0[j] = mk2(0.f, 0.f);
      av1[j] = mk2(0.f, 0.f);
    }
    const float* wp = W + (size_t)c * (H_DIM * V_DIM) + v0;
    for (int hh = 0; hh < H_DIM; hh += 8) {
      float2 w8[8];
#pragma unroll
      for (int u = 0; u < 8; ++u)
        w8[u] = *(const float2*)(wp + (size_t)(hh + u) * V_DIM);
#pragma unroll
      for (int u = 0; u < 8; ++u)
        gv_h(w8[u], &tbf[hh + u][0], av0, av1);
    }
#pragma unroll
    for (int j = 0; j < 8; ++j) {
      float2 oA; oA.x = av0[j].x; oA.y = av1[j].x;    // b = b0+2j
      *(float2*)&sums[((size_t)c * B_DIM + b0 + 2 * j) * V_DIM + v0] = oA;
      float2 oB; oB.x = av0[j].y; oB.y = av1[j].y;    // b = b0+2j+1
      *(float2*)&sums[((size_t)c * B_DIM + b0 + 2 * j + 1) * V_DIM + v0] = oB;
    }
  }
}

// =====================================================================
// k_gumbel_v: v = categorical over c (gumbel + first-max argmax),
// reading the staged sums. Expressions/RNG identical to R11 epilogue.
// =====================================================================
__global__ __launch_bounds__(256, 4) void k_gumbel_v(
    const float* __restrict__ sums, const float* __restrict__ b2,
    uint8_t* __restrict__ idx_out, uint32_t key0, uint32_t key1) {
  int gidx = blockIdx.x * 256 + threadIdx.x;
  int b = gidx >> 7;
  int v0 = (gidx & 127) << 2;
  float best[4];
  uint32_t bc = 0;
#pragma unroll
  for (int c = 0; c < C_DIM; ++c) {
    float4 av = *(const float4*)&sums[((size_t)c * B_DIM + b) * V_DIM + v0];
    float4 bv = *(const float4*)&b2[c * V_DIM + v0];
    uint32_t ib = ((uint32_t)b * C_DIM + (uint32_t)c) * V_DIM + (uint32_t)v0;
    float avq[4] = {av.x, av.y, av.z, av.w};
    float bvq[4] = {bv.x, bv.y, bv.z, bv.w};
#pragma unroll
    for (int q = 0; q < 4; ++q) {
      float uf = bits_to_unit_float(rng_bits(key0, key1, ib + (uint32_t)q));
      if (uf == 0.0f) uf = 1.17549435e-38f;        // u + tiny semantics
      float gz = -xla_log(-xla_log(uf));
      float z = gz + (avq[q] + bvq[q]);
      if (c == 0 || z > best[q]) {
        best[q] = z;
        bc = (bc & ~(0xFFu << (8 * q))) | ((uint32_t)c << (8 * q));
      }
    }
  }
  *(uint32_t*)(idx_out + (size_t)b * V_DIM + v0) = bc;
}

// idx -> one-hot f32 (B,C,V)
__global__ __launch_bounds__(256) void k_onehot(const uint8_t* __restrict__ idx,
                                                float* __restrict__ out) {
  int t = blockIdx.x * 256 + threadIdx.x;     // b*C*V + c*V + v
  int v = t & 511; int rest = t >> 9; int c = rest % C_DIM; int b = rest / C_DIM;
  out[t] = (idx[(size_t)b * V_DIM + v] == c) ? 1.0f : 0.0f;
}

// ---------------- launch ----------------

extern "C" void kernel_launch(void* const* d_in, const int* in_sizes, int n_in,
                              void* d_out, int out_size, void* d_ws, size_t ws_size,
                              hipStream_t stream) {
  float* out = (float*)d_out;

  // ---- structural sentinels ----
  const size_t WS_NEED = 2621440ull      // Wt
                       + 2621440ull      // (reserved, layout kept)
                       + 8388608ull      // idx
                       + 524288ull;      // mask  = 14,155,776 B
  float D = 0.0f;
  if (n_in < 4)                       D = 910.0f + (float)n_in;
  else if (in_sizes[0] != 41943040)   D = 920.0f;
  else if (in_sizes[1] != 655360)     D = 921.0f;
  else if (in_sizes[2] != 2560)       D = 922.0f;
  else if (in_sizes[3] != 256)        D = 923.0f;
  else if (out_size != 50331648)      D = 930.0f + (float)out_size * 1e-6f;
  else if (ws_size < WS_NEED)         D = 100.0f + (float)(ws_size >> 20);
  if (D != 0.0f) {
    hipLaunchKernelGGL(k_sentinel, dim3(1), dim3(1), 0, stream, out, D);
    return;
  }

  const float* v0 = (const float*)d_in[0];
  const float* W  = (const float*)d_in[1];
  const float* b2 = (const float*)d_in[2];   // (C,V)
  const float* c1 = (const float*)d_in[3];   // (H)

  float* out_v  = out;                                         // B*C*V
  float* out_h  = out + (size_t)B_DIM * C_DIM * V_DIM;         // B*H (final h)
  float* out_h0 = out_h + (size_t)B_DIM * H_DIM;               // B*H (h|v0)

  char* ws = (char*)d_ws;
  float*    Wt   = (float*)(ws);                    // 2,621,440 B
  uint8_t*  idx  = (uint8_t*)(ws + 5242880);        // 8,388,608 B
  uint32_t* mask = (uint32_t*)(ws + 13631488);      //   524,288 B

  // sums scratch lives in the out_v region (167.77MB, exact fit);
  // k_onehot overwrites it as the final kernel.
  float* sums = out_v;

  // partitionable (fold-like) split of key(42) into 5 subkeys
  uint32_t keys[5][2];
  for (int i = 0; i < 5; ++i) {
    TFOut r = tf2x32(0u, 42u, 0u, (uint32_t)i);
    keys[i][0] = r.a; keys[i][1] = r.b;
  }

  hipLaunchKernelGGL(k_wt,  dim3(2560),  dim3(256), 0, stream, W, Wt);
  hipLaunchKernelGGL(k_idx, dim3(32768), dim3(256), 0, stream, v0, idx);

  // h0 = sample_h(keys[0], v0) -> h_given_v0 output + mask
  hipLaunchKernelGGL(k_sample_h, dim3(B_DIM), dim3(256), 0, stream,
                     Wt, c1, idx, out_h0, mask, keys[0][0], keys[0][1]);
  // iter 0: v = sample_v(keys[1], h0); h1 = sample_h(keys[2], v)
  hipLaunchKernelGGL(k_gemm_v, dim3(B_DIM / 16), dim3(256), 0, stream,
                     W, mask, sums);
  hipLaunchKernelGGL(k_gumbel_v, dim3(B_DIM * 128 / 256), dim3(256), 0, stream,
                     sums, b2, idx, keys[1][0], keys[1][1]);
  hipLaunchKernelGGL(k_sample_h, dim3(B_DIM), dim3(256), 0, stream,
                     Wt, c1, idx, (float*)nullptr, mask, keys[2][0], keys[2][1]);
  // iter 1: v = sample_v(keys[3], h1); h2 = sample_h(keys[4], v)
  hipLaunchKernelGGL(k_gemm_v, dim3(B_DIM / 16), dim3(256), 0, stream,
                     W, mask, sums);
  hipLaunchKernelGGL(k_gumbel_v, dim3(B_DIM * 128 / 256), dim3(256), 0, stream,
                     sums, b2, idx, keys[3][0], keys[3][1]);
  hipLaunchKernelGGL(k_sample_h, dim3(B_DIM), dim3(256), 0, stream,
                     Wt, c1, idx, out_h, mask, keys[4][0], keys[4][1]);
  // final v one-hot output
  hipLaunchKernelGGL(k_onehot, dim3(163840), dim3(256), 0, stream, idx, out_v);
}

// Round 7
// 1979.615 us; speedup vs baseline: 3.1647x; 1.0269x over previous
//
#include <hip/hip_runtime.h>
#include <cstdint>
#include <cstddef>

// =====================================================================
// RBM Gibbs sampling, bit-exact replication of JAX-on-CPU reference.
// ROUND 17 (perf): k_gemm_v retiled. R16 counters: sample_h is L2-BW
// bound (8.4GB @ ~24TB/s, 70% of L2 ceiling) -- structural limit for
// the sparse scheme, keep. gemm_v (~350us) pays ~5x its 68us VALU
// floor in operand delivery: 4 broadcast ds_read_b128 per (c,h) per
// wave feed only 32 cyc of pk_fma, tbf re-read per c, float2 W loads.
// New tiling: thread = 16 b x 4 v (same 4 b128 feed 64 cyc VALU),
// block = 256 thr = 2 b-groups x 2 v-halves = 32 b x 512 v,
// tbf[256][32] (32KB LDS), W via dwordx4 + h-unroll 4 prefetch,
// grid 512 (2 blocks/CU, 8 waves/CU). Waves in the same v-half read
// identical W lines -> L1 catches the group re-read.
// Bit-exactness: identical h-ascending fma chain per (b,v), f in
// {0,1} exact (+/-0 adds, acc never -0.0), pk lanes = independent b
// chains; only the tiling changed. sample_h/gumbel/onehot = R16.
// Semantics FROZEN (rounds 6-16 passed, absmax=0):
//  - threefry2x32 partitionable; fold-like split; seed(42)->(0,42).
//  - cephes-Horner exp, Pommier-Horner log (q1/q2 tail), no contract.
//  - sigmoid = 1/(1+exp(-x)) IEEE div; gumbel tiny-clamp; first-max
//    argmax; bernoulli u<p; v-GEMM K=256 single sequential chain.
//  - h-GEMM: Eigen gebp kc=320 slab fold, k ascending (c-major).
// ws layout unchanged; sums scratch in out_v region (167.77MB exact);
// sentinel reads back ws_size as absmax if short.
// =====================================================================

#define B_DIM 16384
#define C_DIM 5
#define H_DIM 256
#define V_DIM 512
#define KC    320   // Eigen MT gebp kc (Zen5 48KB L1d: min(435,320)=320)

struct TFOut { uint32_t a, b; };

typedef float f32x2 __attribute__((ext_vector_type(2)));
typedef float f32x4 __attribute__((ext_vector_type(4)));

static __device__ inline f32x2 mk2(float x, float y) {
  f32x2 r; r.x = x; r.y = y; return r;
}

static __device__ inline f32x2 pkfma(f32x2 a, f32x2 b, f32x2 c) {
#if __has_builtin(__builtin_elementwise_fma)
  return __builtin_elementwise_fma(a, b, c);
#else
  f32x2 r; r.x = fmaf(a.x, b.x, c.x); r.y = fmaf(a.y, b.y, c.y); return r;
#endif
}

__host__ __device__ static inline TFOut tf2x32(uint32_t k0, uint32_t k1,
                                               uint32_t c0, uint32_t c1) {
  uint32_t ks2 = k0 ^ k1 ^ 0x1BD11BDAu;
  uint32_t x0 = c0 + k0, x1 = c1 + k1;
#define TF_R(r) { x0 += x1; x1 = (x1 << r) | (x1 >> (32 - r)); x1 ^= x0; }
  TF_R(13) TF_R(15) TF_R(26) TF_R(6)
  x0 += k1;  x1 += ks2 + 1u;
  TF_R(17) TF_R(29) TF_R(16) TF_R(24)
  x0 += ks2; x1 += k0 + 2u;
  TF_R(13) TF_R(15) TF_R(26) TF_R(6)
  x0 += k0;  x1 += k1 + 3u;
  TF_R(17) TF_R(29) TF_R(16) TF_R(24)
  x0 += k1;  x1 += ks2 + 4u;
  TF_R(13) TF_R(15) TF_R(26) TF_R(6)
  x0 += ks2; x1 += k0 + 5u;
#undef TF_R
  TFOut o; o.a = x0; o.b = x1; return o;
}

// partitionable random_bits, 32-bit width, element index i (< 2^32)
__device__ static inline uint32_t rng_bits(uint32_t k0, uint32_t k1, uint32_t i) {
  TFOut r = tf2x32(k0, k1, 0u, i);
  return r.a ^ r.b;
}

__device__ static inline float bits_to_unit_float(uint32_t bits) {
  return __uint_as_float((bits >> 9) | 0x3F800000u) - 1.0f;
}

// XLA GenerateVF32Exp replica (cephes Horner port), mul+add separate,
// NO contraction.
__device__ static float xla_exp(float x_in) {
#pragma clang fp contract(off)
  float x = fminf(x_in, 88.3762626647950f);
  x = fmaxf(x, -88.3762626647949f);
  float fx = floorf(x * 1.44269504088896341f + 0.5f);
  float tmp = fx * 0.693359375f;
  float z = fx * -2.12194440e-4f;
  x = x - tmp;
  x = x - z;
  z = x * x;
  float y = 1.9875691500e-4f;
  y = y * x + 1.3981999507e-3f;
  y = y * x + 8.3334519073e-3f;
  y = y * x + 4.1665795894e-2f;
  y = y * x + 1.6666665459e-1f;
  y = y * x + 5.0000001201e-1f;
  y = y * z + x;
  y = y + 1.0f;
  int n = (int)fx;
  y = y * __uint_as_float((uint32_t)(n + 127) << 23);
  return y;
}

// XLA GenerateVF32Log replica = Pommier/Eigen3.3 log_ps (Horner + tail:
// y+=e*q1; y-=0.5*z; x+=y; x+=e*q2). NO contraction.
__device__ static float xla_log(float x_in) {
#pragma clang fp contract(off)
  float xv = fmaxf(x_in, 1.17549435e-38f);      // min_norm_pos clamp
  uint32_t bits = __float_as_uint(xv);
  float e = (float)((int)(bits >> 23) - 126);
  float x = __uint_as_float((bits & 0x007FFFFFu) | 0x3F000000u);  // [0.5,1)
  bool m = (x < 0.707106781186547524f);
  float tmp = m ? x : 0.0f;
  x = x - 1.0f;
  e = e - (m ? 1.0f : 0.0f);
  x = x + tmp;
  float z = x * x;
  float y = 7.0376836292e-2f;
  y = y * x + -1.1514610310e-1f;
  y = y * x + 1.1676998740e-1f;
  y = y * x + -1.2420140846e-1f;
  y = y * x + 1.4249322787e-1f;
  y = y * x + -1.6668057665e-1f;
  y = y * x + 2.0000714765e-1f;
  y = y * x + -2.4999993993e-1f;
  y = y * x + 3.3333331174e-1f;
  y = y * x;
  y = y * z;
  float t1 = e * -2.12194440e-4f;
  y = y + t1;
  float t2 = z * 0.5f;
  y = y - t2;
  x = x + y;
  float t3 = e * 0.693359375f;
  x = x + t3;
  return x;
}

// ---------------- kernels ----------------

__global__ void k_sentinel(float* out, float d) {
  out[0] = d;
}

// v0 one-hot (B,C,V) -> idx (B,V) u8
__global__ __launch_bounds__(256) void k_idx(const float* __restrict__ v0,
                                             uint8_t* __restrict__ idx) {
  int t = blockIdx.x * 256 + threadIdx.x;          // b*V + v
  int b = t >> 9, v = t & 511;
  const float* p = v0 + (size_t)b * (C_DIM * V_DIM) + v;
  int cf = 0;
#pragma unroll
  for (int c = 0; c < C_DIM; ++c)
    if (p[c * V_DIM] > 0.5f) cf = c;
  idx[t] = (uint8_t)cf;
}

// W (c,h,v) -> Wt (c,v,h)
__global__ __launch_bounds__(256) void k_wt(const float* __restrict__ W,
                                            float* __restrict__ Wt) {
  int t = blockIdx.x * 256 + threadIdx.x;          // (c, v, h)
  int h = t & 255; int rest = t >> 8; int v = rest & 511; int c = rest >> 9;
  Wt[t] = W[((size_t)c * H_DIM + h) * V_DIM + v];
}

// =====================================================================
// k_sample_h: R11 sparse per-b kernel (measured ~345us, L2-BW bound
// at ~70% of L2 ceiling -- structural limit for this scheme).
// h = bernoulli(sigmoid(kc-slab-folded k-ascending sum + c1)).
// =====================================================================
__global__ __launch_bounds__(256) void k_sample_h(
    const float* __restrict__ Wt, const float* __restrict__ c1,
    const uint8_t* __restrict__ idx,
    float* __restrict__ out_h, uint32_t* __restrict__ out_mask,
    uint32_t key0, uint32_t key1) {
  __shared__ uint8_t  sidx[V_DIM];
  __shared__ uint32_t soff[V_DIM];     // (c*512+v)*1024 byte offsets, k asc
  __shared__ uint16_t cnt[8][5];       // per 64-lane segment, per class
  __shared__ uint16_t base[8][5];      // global start position
  __shared__ uint16_t jb[10];          // panel boundaries in j-space
  int b = blockIdx.x;
  int t = threadIdx.x;
  if (t < 128)
    ((uint32_t*)sidx)[t] = ((const uint32_t*)(idx + (size_t)b * V_DIM))[t];
  __syncthreads();

  int lane = t & 63, wv = t >> 6;
  int v0 = t,       c0 = sidx[v0];
  int v1 = t + 256, c1i = sidx[v1];
  int rank0, rank1;
  {
    unsigned long long bal[5];
#pragma unroll
    for (int cc = 0; cc < 5; ++cc) bal[cc] = __ballot(c0 == cc);
    if (lane == 0) {
#pragma unroll
      for (int cc = 0; cc < 5; ++cc) cnt[wv][cc] = (uint16_t)__popcll(bal[cc]);
    }
    rank0 = (int)__popcll(bal[c0] & ((1ull << lane) - 1ull));
  }
  {
    unsigned long long bal[5];
#pragma unroll
    for (int cc = 0; cc < 5; ++cc) bal[cc] = __ballot(c1i == cc);
    if (lane == 0) {
#pragma unroll
      for (int cc = 0; cc < 5; ++cc) cnt[4 + wv][cc] = (uint16_t)__popcll(bal[cc]);
    }
    rank1 = (int)__popcll(bal[c1i] & ((1ull << lane) - 1ull));
  }
  __syncthreads();
  if (t == 0) {
    int pos = 0;
    for (int cc = 0; cc < 5; ++cc)
      for (int g = 0; g < 8; ++g) { base[g][cc] = (uint16_t)pos; pos += cnt[g][cc]; }
  }
  __syncthreads();
  soff[base[wv][c0] + rank0]       = (uint32_t)(c0 * V_DIM + v0) << 10;   // k*1024B
  soff[base[4 + wv][c1i] + rank1]  = (uint32_t)(c1i * V_DIM + v1) << 10;
  __syncthreads();
  if (t < 10) {
    uint32_t target = (uint32_t)(t * KC) << 10;
    int lo = 0, hi = V_DIM;
    while (lo < hi) { int mid = (lo + hi) >> 1;
      if (soff[mid] < target) lo = mid + 1; else hi = mid; }
    jb[t] = (uint16_t)lo;
  }
  __syncthreads();

  // main accumulation: h = t
  const char* Wh = (const char*)Wt + (size_t)t * 4;
  float total = 0.0f;
  for (int s = 0; s < 9; ++s) {
    int j = jb[s], jend = jb[s + 1];
    float psum = 0.0f;
    for (; j + 4 <= jend; j += 4) {
      float w0 = *(const float*)(Wh + soff[j]);
      float w1 = *(const float*)(Wh + soff[j + 1]);
      float w2 = *(const float*)(Wh + soff[j + 2]);
      float w3 = *(const float*)(Wh + soff[j + 3]);
      psum += w0; psum += w1; psum += w2; psum += w3;
    }
    for (; j < jend; ++j) psum += *(const float*)(Wh + soff[j]);
    total += psum;
  }

  float tt = total + c1[t];
  float p = 1.0f / (1.0f + xla_exp(-tt));   // IEEE div, logistic exp form

  uint32_t i = (uint32_t)(b * H_DIM + t);
  float u = bits_to_unit_float(rng_bits(key0, key1, i));
  bool hb = (u < p);
  if (out_h) out_h[(size_t)b * H_DIM + t] = hb ? 1.0f : 0.0f;

  unsigned long long m = __ballot(hb);
  if ((t & 63) == 0) {
    out_mask[(size_t)b * 8 + wv * 2 + 0] = (uint32_t)(m & 0xFFFFFFFFull);
    out_mask[(size_t)b * 8 + wv * 2 + 1] = (uint32_t)(m >> 32);
  }
}

// =====================================================================
// k_gemm_v (R17): sums[c][b][v] = h-ascending dense fma chain.
// Block = 256 thr = 2 b-groups x 2 v-halves = 32 b x 512 v.
// Thread = 16 b (8 pk pairs) x 4 v. Per (c,h) per wave: 4 broadcast
// ds_read_b128 (its group's 16 f-floats) + 1 dwordx4 W + 32 pk_fma.
// tbf[256][32] floats (32KB LDS), no barriers in main loop, h-unroll
// 4 with W prefetch. Grid 512 (2 blocks/CU). Chain bit-identical.
// =====================================================================
__global__ __launch_bounds__(256, 2) void k_gemm_v(
    const float* __restrict__ W, const uint32_t* __restrict__ mask,
    float* __restrict__ sums) {
  __shared__ uint32_t smask[32][8];
  __shared__ __align__(16) float tbf[H_DIM][32];
  int t = threadIdx.x;
  int b0 = blockIdx.x * 32;
  smask[t >> 3][t & 7] = mask[(size_t)b0 * 8 + t];
  __syncthreads();
  {
    int h = t;
    uint32_t w = (uint32_t)(h >> 5), s = (uint32_t)(h & 31);
#pragma unroll
    for (int j = 0; j < 32; ++j)
      tbf[h][j] = (float)((smask[j][w] >> s) & 1u);
  }
  __syncthreads();

  int wv = t >> 6, lane = t & 63;
  int g = wv >> 1, vh = wv & 1;
  int v0 = vh * 256 + (lane << 2);
  int bg = b0 + g * 16;

  for (int c = 0; c < C_DIM; ++c) {
    f32x2 acc[8][4];
#pragma unroll
    for (int p = 0; p < 8; ++p)
#pragma unroll
      for (int q = 0; q < 4; ++q) acc[p][q] = mk2(0.f, 0.f);

    const float* wp = W + (size_t)c * (H_DIM * V_DIM) + v0;
    for (int hh = 0; hh < H_DIM; hh += 4) {
      float4 w4[4];
#pragma unroll
      for (int u = 0; u < 4; ++u)
        w4[u] = *(const float4*)(wp + (size_t)(hh + u) * V_DIM);
#pragma unroll
      for (int u = 0; u < 4; ++u) {
        const f32x4* fp = (const f32x4*)&tbf[hh + u][g * 16];
        f32x4 qA = fp[0], qB = fp[1], qC = fp[2], qD = fp[3];
        f32x2 f0 = __builtin_shufflevector(qA, qA, 0, 1);
        f32x2 f1 = __builtin_shufflevector(qA, qA, 2, 3);
        f32x2 f2 = __builtin_shufflevector(qB, qB, 0, 1);
        f32x2 f3 = __builtin_shufflevector(qB, qB, 2, 3);
        f32x2 f4 = __builtin_shufflevector(qC, qC, 0, 1);
        f32x2 f5 = __builtin_shufflevector(qC, qC, 2, 3);
        f32x2 f6 = __builtin_shufflevector(qD, qD, 0, 1);
        f32x2 f7 = __builtin_shufflevector(qD, qD, 2, 3);
        f32x2 wwx = mk2(w4[u].x, w4[u].x);
        f32x2 wwy = mk2(w4[u].y, w4[u].y);
        f32x2 wwz = mk2(w4[u].z, w4[u].z);
        f32x2 www = mk2(w4[u].w, w4[u].w);
        acc[0][0] = pkfma(wwx, f0, acc[0][0]); acc[0][1] = pkfma(wwy, f0, acc[0][1]);
        acc[0][2] = pkfma(wwz, f0, acc[0][2]); acc[0][3] = pkfma(www, f0, acc[0][3]);
        acc[1][0] = pkfma(wwx, f1, acc[1][0]); acc[1][1] = pkfma(wwy, f1, acc[1][1]);
        acc[1][2] = pkfma(wwz, f1, acc[1][2]); acc[1][3] = pkfma(www, f1, acc[1][3]);
        acc[2][0] = pkfma(wwx, f2, acc[2][0]); acc[2][1] = pkfma(wwy, f2, acc[2][1]);
        acc[2][2] = pkfma(wwz, f2, acc[2][2]); acc[2][3] = pkfma(www, f2, acc[2][3]);
        acc[3][0] = pkfma(wwx, f3, acc[3][0]); acc[3][1] = pkfma(wwy, f3, acc[3][1]);
        acc[3][2] = pkfma(wwz, f3, acc[3][2]); acc[3][3] = pkfma(www, f3, acc[3][3]);
        acc[4][0] = pkfma(wwx, f4, acc[4][0]); acc[4][1] = pkfma(wwy, f4, acc[4][1]);
        acc[4][2] = pkfma(wwz, f4, acc[4][2]); acc[4][3] = pkfma(www, f4, acc[4][3]);
        acc[5][0] = pkfma(wwx, f5, acc[5][0]); acc[5][1] = pkfma(wwy, f5, acc[5][1]);
        acc[5][2] = pkfma(wwz, f5, acc[5][2]); acc[5][3] = pkfma(www, f5, acc[5][3]);
        acc[6][0] = pkfma(wwx, f6, acc[6][0]); acc[6][1] = pkfma(wwy, f6, acc[6][1]);
        acc[6][2] = pkfma(wwz, f6, acc[6][2]); acc[6][3] = pkfma(www, f6, acc[6][3]);
        acc[7][0] = pkfma(wwx, f7, acc[7][0]); acc[7][1] = pkfma(wwy, f7, acc[7][1]);
        acc[7][2] = pkfma(wwz, f7, acc[7][2]); acc[7][3] = pkfma(www, f7, acc[7][3]);
      }
    }
    // stores: pair p covers b = bg + 2p (+1 in .y lanes)
#pragma unroll
    for (int p = 0; p < 8; ++p) {
      float4 oA, oB;
      oA.x = acc[p][0].x; oA.y = acc[p][1].x; oA.z = acc[p][2].x; oA.w = acc[p][3].x;
      oB.x = acc[p][0].y; oB.y = acc[p][1].y; oB.z = acc[p][2].y; oB.w = acc[p][3].y;
      *(float4*)&sums[((size_t)c * B_DIM + bg + 2 * p) * V_DIM + v0] = oA;
      *(float4*)&sums[((size_t)c * B_DIM + bg + 2 * p + 1) * V_DIM + v0] = oB;
    }
  }
}

// =====================================================================
// k_gumbel_v: v = categorical over c (gumbel + first-max argmax),
// reading the staged sums. Expressions/RNG identical to R11 epilogue.
// =====================================================================
__global__ __launch_bounds__(256, 4) void k_gumbel_v(
    const float* __restrict__ sums, const float* __restrict__ b2,
    uint8_t* __restrict__ idx_out, uint32_t key0, uint32_t key1) {
  int gidx = blockIdx.x * 256 + threadIdx.x;
  int b = gidx >> 7;
  int v0 = (gidx & 127) << 2;
  float best[4];
  uint32_t bc = 0;
#pragma unroll
  for (int c = 0; c < C_DIM; ++c) {
    float4 av = *(const float4*)&sums[((size_t)c * B_DIM + b) * V_DIM + v0];
    float4 bv = *(const float4*)&b2[c * V_DIM + v0];
    uint32_t ib = ((uint32_t)b * C_DIM + (uint32_t)c) * V_DIM + (uint32_t)v0;
    float avq[4] = {av.x, av.y, av.z, av.w};
    float bvq[4] = {bv.x, bv.y, bv.z, bv.w};
#pragma unroll
    for (int q = 0; q < 4; ++q) {
      float uf = bits_to_unit_float(rng_bits(key0, key1, ib + (uint32_t)q));
      if (uf == 0.0f) uf = 1.17549435e-38f;        // u + tiny semantics
      float gz = -xla_log(-xla_log(uf));
      float z = gz + (avq[q] + bvq[q]);
      if (c == 0 || z > best[q]) {
        best[q] = z;
        bc = (bc & ~(0xFFu << (8 * q))) | ((uint32_t)c << (8 * q));
      }
    }
  }
  *(uint32_t*)(idx_out + (size_t)b * V_DIM + v0) = bc;
}

// idx -> one-hot f32 (B,C,V)
__global__ __launch_bounds__(256) void k_onehot(const uint8_t* __restrict__ idx,
                                                float* __restrict__ out) {
  int t = blockIdx.x * 256 + threadIdx.x;     // b*C*V + c*V + v
  int v = t & 511; int rest = t >> 9; int c = rest % C_DIM; int b = rest / C_DIM;
  out[t] = (idx[(size_t)b * V_DIM + v] == c) ? 1.0f : 0.0f;
}

// ---------------- launch ----------------

extern "C" void kernel_launch(void* const* d_in, const int* in_sizes, int n_in,
                              void* d_out, int out_size, void* d_ws, size_t ws_size,
                              hipStream_t stream) {
  float* out = (float*)d_out;

  // ---- structural sentinels ----
  const size_t WS_NEED = 2621440ull      // Wt
                       + 2621440ull      // (reserved, layout kept)
                       + 8388608ull      // idx
                       + 524288ull;      // mask  = 14,155,776 B
  float D = 0.0f;
  if (n_in < 4)                       D = 910.0f + (float)n_in;
  else if (in_sizes[0] != 41943040)   D = 920.0f;
  else if (in_sizes[1] != 655360)     D = 921.0f;
  else if (in_sizes[2] != 2560)       D = 922.0f;
  else if (in_sizes[3] != 256)        D = 923.0f;
  else if (out_size != 50331648)      D = 930.0f + (float)out_size * 1e-6f;
  else if (ws_size < WS_NEED)         D = 100.0f + (float)(ws_size >> 20);
  if (D != 0.0f) {
    hipLaunchKernelGGL(k_sentinel, dim3(1), dim3(1), 0, stream, out, D);
    return;
  }

  const float* v0 = (const float*)d_in[0];
  const float* W  = (const float*)d_in[1];
  const float* b2 = (const float*)d_in[2];   // (C,V)
  const float* c1 = (const float*)d_in[3];   // (H)

  float* out_v  = out;                                         // B*C*V
  float* out_h  = out + (size_t)B_DIM * C_DIM * V_DIM;         // B*H (final h)
  float* out_h0 = out_h + (size_t)B_DIM * H_DIM;               // B*H (h|v0)

  char* ws = (char*)d_ws;
  float*    Wt   = (float*)(ws);                    // 2,621,440 B
  uint8_t*  idx  = (uint8_t*)(ws + 5242880);        // 8,388,608 B
  uint32_t* mask = (uint32_t*)(ws + 13631488);      //   524,288 B

  // sums scratch lives in the out_v region (167.77MB, exact fit);
  // k_onehot overwrites it as the final kernel.
  float* sums = out_v;

  // partitionable (fold-like) split of key(42) into 5 subkeys
  uint32_t keys[5][2];
  for (int i = 0; i < 5; ++i) {
    TFOut r = tf2x32(0u, 42u, 0u, (uint32_t)i);
    keys[i][0] = r.a; keys[i][1] = r.b;
  }

  hipLaunchKernelGGL(k_wt,  dim3(2560),  dim3(256), 0, stream, W, Wt);
  hipLaunchKernelGGL(k_idx, dim3(32768), dim3(256), 0, stream, v0, idx);

  // h0 = sample_h(keys[0], v0) -> h_given_v0 output + mask
  hipLaunchKernelGGL(k_sample_h, dim3(B_DIM), dim3(256), 0, stream,
                     Wt, c1, idx, out_h0, mask, keys[0][0], keys[0][1]);
  // iter 0: v = sample_v(keys[1], h0); h1 = sample_h(keys[2], v)
  hipLaunchKernelGGL(k_gemm_v, dim3(B_DIM / 32), dim3(256), 0, stream,
                     W, mask, sums);
  hipLaunchKernelGGL(k_gumbel_v, dim3(B_DIM * 128 / 256), dim3(256), 0, stream,
                     sums, b2, idx, keys[1][0], keys[1][1]);
  hipLaunchKernelGGL(k_sample_h, dim3(B_DIM), dim3(256), 0, stream,
                     Wt, c1, idx, (float*)nullptr, mask, keys[2][0], keys[2][1]);
  // iter 1: v = sample_v(keys[3], h1); h2 = sample_h(keys[4], v)
  hipLaunchKernelGGL(k_gemm_v, dim3(B_DIM / 32), dim3(256), 0, stream,
                     W, mask, sums);
  hipLaunchKernelGGL(k_gumbel_v, dim3(B_DIM * 128 / 256), dim3(256), 0, stream,
                     sums, b2, idx, keys[3][0], keys[3][1]);
  hipLaunchKernelGGL(k_sample_h, dim3(B_DIM), dim3(256), 0, stream,
                     Wt, c1, idx, out_h, mask, keys[4][0], keys[4][1]);
  // final v one-hot output
  hipLaunchKernelGGL(k_onehot, dim3(163840), dim3(256), 0, stream, idx, out_v);
}